// Round 9
// baseline (40.846 us; speedup 1.0000x reference)
//
#include <hip/hip_runtime.h>
#include <cmath>

// RTMDet decode, fused: async global_load_lds 4-deep pipeline for the cls scan.
// Per spatial position: conf = sigmoid(max_c logit), class = argmax_c logit (first occurrence),
// box = clip([gx-l, gy-t, gx+r, gy+d], 0, 639), gx = w*step, gy = h*step.
// Output layout (flat float32 in d_out): boxes [64,8400,4] | scores [64,8400] | classes [64,8400].
//
// R8 post-mortem: every register-based pipeline collapsed (VGPR stuck at 32); MLP was never
// actually raised. Here the pipeline lives in LDS via __builtin_amdgcn_global_load_lds
// (width 16, vmcnt-tracked, zero VGPR cost): 80 classes = 20 chunks x 4 float4 per thread,
// 4 chunks in flight (12 outstanding loads/wave steady-state, counted s_waitcnt vmcnt(12),
// never drained to 0 mid-loop). Each thread stages and reads ONLY its own LDS slot
// (sb[chunk&3][k*256+tid]) -> no cross-wave sharing -> no barriers at all.
// LDS dest is linear base+lane*16 (m104 rule). Box path runs after the pipeline drains.
//
// Grid: 525 blocks x 256 threads (1 quad/thread), level boundaries on block boundaries:
//   [0,400) -> level 0 (80x80, s8) | [400,500) -> level 1 (40x40, s16) | [500,525) -> lvl 2.

constexpr int B_   = 64;
constexpr int NC   = 80;
constexpr int NTOT = 8400;   // 6400 + 1600 + 400

typedef float f32x4 __attribute__((ext_vector_type(4)));

__device__ __forceinline__ float sigmoidf_(float x) { return 1.0f / (1.0f + __expf(-x)); }

__device__ __forceinline__ void gld16(const void* g, void* l) {
    __builtin_amdgcn_global_load_lds(
        (const __attribute__((address_space(1))) void*)g,
        (__attribute__((address_space(3))) void*)l, 16, 0, 0);
}

template<int HW, int W, int STEP, int NOFF>
__device__ __forceinline__ void decode_level(
    const float* __restrict__ cls, const float* __restrict__ box,
    float* __restrict__ oboxes, float* __restrict__ oscores, float* __restrict__ oclasses,
    int lbid, int tid, f32x4* __restrict__ sb /* [4][4*256] = 64 KB */)
{
    constexpr int QPI = HW / 4;                 // quads per image
    constexpr int PPI = HW / 2;                 // pairs per image

    int Q = lbid * 256 + tid;                   // level-local quad (1 quad per thread)
    int b = Q / QPI;                            // compile-time QPI -> magic mul
    int p = (Q - b * QPI) << 2;                 // first of 4 consecutive positions

    const float* gsrc = cls + (size_t)b * NC * HW + p;   // class c lives at gsrc + c*HW

    float m[4]  = {-3.4e38f, -3.4e38f, -3.4e38f, -3.4e38f};
    int   ci[4] = {0, 0, 0, 0};

    // stage chunk ch (classes 4ch..4ch+3) into LDS buffer ch&3, this thread's private slots
#define STAGE(ch) {                                                        \
        const float* s_ = gsrc + (size_t)(ch) * 4 * HW;                    \
        f32x4* d_ = sb + ((ch) & 3) * 1024 + tid;                          \
        gld16(s_,            d_);                                          \
        gld16(s_ +     HW,   d_ + 256);                                    \
        gld16(s_ + 2 * HW,   d_ + 512);                                    \
        gld16(s_ + 3 * HW,   d_ + 768);                                    \
    }

#define RED1(v, c) {                                                       \
        if (v.x > m[0]) { m[0] = v.x; ci[0] = (c); }                       \
        if (v.y > m[1]) { m[1] = v.y; ci[1] = (c); }                       \
        if (v.z > m[2]) { m[2] = v.z; ci[2] = (c); }                       \
        if (v.w > m[3]) { m[3] = v.w; ci[3] = (c); }                       \
    }

    // wait until chunk i's 4 loads landed (later chunks may stay in flight), consume, restage
#define CHUNK(i, WN) {                                                     \
        asm volatile("s_waitcnt vmcnt(" #WN ")" ::: "memory");             \
        const f32x4* bp = sb + ((i) & 3) * 1024 + tid;                     \
        f32x4 v0 = bp[0], v1 = bp[256], v2 = bp[512], v3 = bp[768];        \
        RED1(v0, (i) * 4 + 0) RED1(v1, (i) * 4 + 1)                        \
        RED1(v2, (i) * 4 + 2) RED1(v3, (i) * 4 + 3)                        \
        if ((i) + 4 < 20) STAGE((i) + 4)                                   \
    }

    STAGE(0) STAGE(1) STAGE(2) STAGE(3)         // prologue: 16 loads in flight

    CHUNK( 0, 12) CHUNK( 1, 12) CHUNK( 2, 12) CHUNK( 3, 12)
    CHUNK( 4, 12) CHUNK( 5, 12) CHUNK( 6, 12) CHUNK( 7, 12)
    CHUNK( 8, 12) CHUNK( 9, 12) CHUNK(10, 12) CHUNK(11, 12)
    CHUNK(12, 12) CHUNK(13, 12) CHUNK(14, 12) CHUNK(15, 12)
    CHUNK(16, 12) CHUNK(17,  8) CHUNK(18,  4) CHUNK(19,  0)

#undef STAGE
#undef RED1
#undef CHUNK

    // ---------- scores / classes: float4, consecutive threads -> consecutive quads ----------
    size_t obase = (size_t)b * NTOT + NOFF + p;
    float4 osc, ocl;
    osc.x = sigmoidf_(m[0]); osc.y = sigmoidf_(m[1]);
    osc.z = sigmoidf_(m[2]); osc.w = sigmoidf_(m[3]);
    ocl.x = (float)ci[0]; ocl.y = (float)ci[1]; ocl.z = (float)ci[2]; ocl.w = (float)ci[3];
    *reinterpret_cast<float4*>(oscores  + obase) = osc;
    *reinterpret_cast<float4*>(oclasses + obase) = ocl;

    // ---------- boxes: 2 pair-units per thread (R6 mapping, coalesced stores) ----------
    #pragma unroll
    for (int s = 0; s < 2; ++s) {
        int PR = lbid * 512 + tid + (s << 8);   // level-local pair, block spans 512 pairs
        int bb = PR / PPI;                      // compile-time PPI -> magic mul
        int pp = (PR - bb * PPI) << 1;
        int hh = pp / W;                        // compile-time W -> magic mul
        int ww = pp - hh * W;

        const float* bbase = box + (size_t)bb * 4 * HW + pp;
        float2 bl = *reinterpret_cast<const float2*>(bbase);
        float2 bt = *reinterpret_cast<const float2*>(bbase + HW);
        float2 br = *reinterpret_cast<const float2*>(bbase + 2 * HW);
        float2 bd = *reinterpret_cast<const float2*>(bbase + 3 * HW);

        float gy = (float)(hh * STEP);
        size_t ob = (size_t)bb * NTOT + NOFF + pp;
        #pragma unroll
        for (int j = 0; j < 2; ++j) {
            float gx = (float)((ww + j) * STEP);
            float l  = j ? bl.y : bl.x;
            float tt = j ? bt.y : bt.x;
            float r  = j ? br.y : br.x;
            float dd = j ? bd.y : bd.x;
            float4 o;
            o.x = fminf(fmaxf(gx - l,  0.0f), 639.0f);
            o.y = fminf(fmaxf(gy - tt, 0.0f), 639.0f);
            o.z = fminf(fmaxf(gx + r,  0.0f), 639.0f);
            o.w = fminf(fmaxf(gy + dd, 0.0f), 639.0f);
            *reinterpret_cast<float4*>(oboxes + (ob + j) * 4) = o;  // coalesced float4
        }
    }
}

__global__ __launch_bounds__(256) void rtmdet_decode_fused(
    const float* __restrict__ cls0, const float* __restrict__ box0,
    const float* __restrict__ cls1, const float* __restrict__ box1,
    const float* __restrict__ cls2, const float* __restrict__ box2,
    float* __restrict__ oboxes, float* __restrict__ oscores, float* __restrict__ oclasses)
{
    __shared__ f32x4 sb[4 * 1024];              // 4 chunks x (4 classes x 256 threads), 64 KB

    int bid = blockIdx.x;
    int tid = threadIdx.x;
    if (bid < 400) {
        decode_level<6400, 80,  8,    0>(cls0, box0, oboxes, oscores, oclasses, bid,       tid, sb);
    } else if (bid < 500) {
        decode_level<1600, 40, 16, 6400>(cls1, box1, oboxes, oscores, oclasses, bid - 400, tid, sb);
    } else {
        decode_level< 400, 20, 32, 8000>(cls2, box2, oboxes, oscores, oclasses, bid - 500, tid, sb);
    }
}

extern "C" void kernel_launch(void* const* d_in, const int* in_sizes, int n_in,
                              void* d_out, int out_size, void* d_ws, size_t ws_size,
                              hipStream_t stream) {
    const float* cls0 = (const float*)d_in[0];
    const float* box0 = (const float*)d_in[1];
    const float* cls1 = (const float*)d_in[2];
    const float* box1 = (const float*)d_in[3];
    const float* cls2 = (const float*)d_in[4];
    const float* box2 = (const float*)d_in[5];

    float* oboxes   = (float*)d_out;
    float* oscores  = oboxes  + (size_t)B_ * NTOT * 4;
    float* oclasses = oscores + (size_t)B_ * NTOT;

    rtmdet_decode_fused<<<525, 256, 0, stream>>>(cls0, box0, cls1, box1, cls2, box2,
                                                 oboxes, oscores, oclasses);
}

// Round 10
// 33.770 us; speedup vs baseline: 1.2095x; 1.2095x over previous
//
#include <hip/hip_runtime.h>
#include <cmath>

// RTMDet decode, fused, 2-positions-per-thread (float2). FINAL (plateau variant, R4).
// Per spatial position: conf = sigmoid(max_c logit), class = argmax_c logit (first occurrence),
// box = clip([gx-l, gy-t, gx+r, gy+d], 0, 639), gx = w*step, gy = h*step.
// Output layout (flat float32 in d_out): boxes [64,8400,4] | scores [64,8400] | classes [64,8400].
//
// Roofline closure (R2-R9): occupancy 8-32 w/CU, 8-16 B/lane widths, 2x VMEM-instr range,
// register pipelines (compiler-collapsed) and a real 16-deep async global_load_lds pipeline
// (regressed: LDS cut residency) all land 33.5-34.0 us. Saturation at 193.5 MB / 33.55 us =
// 5.77 TB/s aggregate = 9.4 B/cyc/CU vs the m13 streaming constant ~10 B/cyc/CU.
// Model: 193.5 MB / 6.29 TB/s = 30.8 us + ~3-4 us graph-node launch cost (measured via the
// 3-node vs 1-node delta in R1->R2) = 33.5-34 us == measured. Memory-bound limit reached.
//
// Grid: 1050 blocks x 256 threads (level boundaries on block boundaries):
//   [0,800)     -> level 0 (80x80, step 8)
//   [800,1000)  -> level 1 (40x40, step 16)
//   [1000,1050) -> level 2 (20x20, step 32)

constexpr int B_   = 64;
constexpr int NC   = 80;
constexpr int NTOT = 8400;   // 6400 + 1600 + 400

__device__ __forceinline__ float sigmoidf_(float x) { return 1.0f / (1.0f + __expf(-x)); }

template<int HW, int W, int STEP, int NOFF>
__device__ __forceinline__ void decode_level(
    const float* __restrict__ cls, const float* __restrict__ box,
    float* __restrict__ oboxes, float* __restrict__ oscores, float* __restrict__ oclasses,
    int lbid, int tid)
{
    constexpr int PPI = HW / 2;                 // pairs per image

    int t = lbid * 256 + tid;                   // pair index in [0, 64*PPI)
    int b = t / PPI;                            // compile-time PPI -> magic mul
    int p = (t - b * PPI) << 1;                 // first of 2 consecutive positions
    int h = p / W;                              // compile-time W -> magic mul
    int w = p - h * W;

    // ---------- hoisted box loads (independent of class loop -> early MLP) ----------
    const float* bbase = box + (size_t)b * 4 * HW + p;
    float2 bl = *reinterpret_cast<const float2*>(bbase);            // l for p, p+1
    float2 bt = *reinterpret_cast<const float2*>(bbase + HW);       // t
    float2 br = *reinterpret_cast<const float2*>(bbase + 2 * HW);   // r
    float2 bd = *reinterpret_cast<const float2*>(bbase + 3 * HW);   // d

    // ---------- class max/argmax: full 80-class scan per thread, float2 loads ----------
    const float* cbase = cls + (size_t)b * NC * HW + p;
    float m[2]  = {-3.4e38f, -3.4e38f};
    int   ci[2] = {0, 0};
    #pragma unroll 16
    for (int c = 0; c < NC; ++c) {
        float2 v = *reinterpret_cast<const float2*>(cbase + (size_t)c * HW);
        if (v.x > m[0]) { m[0] = v.x; ci[0] = c; }   // strict > : first occurrence
        if (v.y > m[1]) { m[1] = v.y; ci[1] = c; }
    }

    // ---------- stores (all lane-contiguous) ----------
    size_t obase = (size_t)b * NTOT + NOFF + p;
    *reinterpret_cast<float2*>(oscores  + obase) = make_float2(sigmoidf_(m[0]), sigmoidf_(m[1]));
    *reinterpret_cast<float2*>(oclasses + obase) = make_float2((float)ci[0], (float)ci[1]);

    float gy = (float)(h * STEP);
    #pragma unroll
    for (int j = 0; j < 2; ++j) {
        float gx = (float)((w + j) * STEP);
        float l  = j ? bl.y : bl.x;
        float tt = j ? bt.y : bt.x;
        float r  = j ? br.y : br.x;
        float dd = j ? bd.y : bd.x;
        float4 o;
        o.x = fminf(fmaxf(gx - l,  0.0f), 639.0f);
        o.y = fminf(fmaxf(gy - tt, 0.0f), 639.0f);
        o.z = fminf(fmaxf(gx + r,  0.0f), 639.0f);
        o.w = fminf(fmaxf(gy + dd, 0.0f), 639.0f);
        *reinterpret_cast<float4*>(oboxes + (obase + j) * 4) = o;   // coalesced float4
    }
}

__global__ __launch_bounds__(256) void rtmdet_decode_fused(
    const float* __restrict__ cls0, const float* __restrict__ box0,
    const float* __restrict__ cls1, const float* __restrict__ box1,
    const float* __restrict__ cls2, const float* __restrict__ box2,
    float* __restrict__ oboxes, float* __restrict__ oscores, float* __restrict__ oclasses)
{
    int bid = blockIdx.x;
    int tid = threadIdx.x;
    if (bid < 800) {
        decode_level<6400, 80,  8,    0>(cls0, box0, oboxes, oscores, oclasses, bid,        tid);
    } else if (bid < 1000) {
        decode_level<1600, 40, 16, 6400>(cls1, box1, oboxes, oscores, oclasses, bid - 800,  tid);
    } else {
        decode_level< 400, 20, 32, 8000>(cls2, box2, oboxes, oscores, oclasses, bid - 1000, tid);
    }
}

extern "C" void kernel_launch(void* const* d_in, const int* in_sizes, int n_in,
                              void* d_out, int out_size, void* d_ws, size_t ws_size,
                              hipStream_t stream) {
    const float* cls0 = (const float*)d_in[0];
    const float* box0 = (const float*)d_in[1];
    const float* cls1 = (const float*)d_in[2];
    const float* box1 = (const float*)d_in[3];
    const float* cls2 = (const float*)d_in[4];
    const float* box2 = (const float*)d_in[5];

    float* oboxes   = (float*)d_out;
    float* oscores  = oboxes  + (size_t)B_ * NTOT * 4;
    float* oclasses = oscores + (size_t)B_ * NTOT;

    rtmdet_decode_fused<<<1050, 256, 0, stream>>>(cls0, box0, cls1, box1, cls2, box2,
                                                  oboxes, oscores, oclasses);
}